// Round 4
// baseline (602.636 us; speedup 1.0000x reference)
//
#include <hip/hip_runtime.h>

namespace {
constexpr int BATCH = 8;
constexpr int WIDTH = 48;
constexpr int N = WIDTH * WIDTH;   // 2304
// PW=56: row stride mod 32 = 24; tile-row stride 3*56 mod 32 = 8. A wave's 4
// tile-row groups sit at bank offsets {0,8,16,24}; the 16-lane column set
// {3k mod 32} covers exactly one of each {b, b+16} bank pair, so every conv
// read/write is a uniform 2-lanes-per-bank pattern (free on CDNA4).
constexpr int PW = 56;
constexpr int PH = 54;             // 48 + 6 halo
constexpr int NT = 256;            // 4 waves; each thread owns a 3x3 pixel tile
constexpr int NWAVE = NT / 64;
constexpr float EPS = 1e-8f;
constexpr int MAX_ITERS = 250;
constexpr float TOLSQ = 1e-10f;    // (1e-5)^2
constexpr int NHALO = 48;          // conv footprint minus the 9 register centers

__device__ constexpr int halo_w(int rho) {
  const int drmin = (rho < 0) ? -rho : (rho > 2 ? rho - 2 : 0);
  return 3 - drmin;
}
// Slot of cell (row rho in [-3,5], col m in [-w,2+w]) in the packed halo array.
__device__ constexpr int h_index(int rho, int m) {
  int idx = 0;
  for (int r2 = -3; r2 < rho; ++r2) {
    int cnt = 2 * halo_w(r2) + 3;
    if (r2 >= 0 && r2 <= 2) cnt -= 3;  // centers excluded
    idx += cnt;
  }
  for (int m2 = -halo_w(rho); m2 < m; ++m2) {
    if (rho >= 0 && rho <= 2 && m2 >= 0 && m2 <= 2) continue;
    idx++;
  }
  return idx;
}
}

__device__ __forceinline__ float wave_sum(float v) {
#pragma unroll
  for (int off = 32; off > 0; off >>= 1) v += __shfl_down(v, off);
  return v;
}

__device__ __forceinline__ float sum4(const float* buf) {
  const float4 a = *(const float4*)buf;  // broadcast b128, conflict-free
  return (a.x + a.y) + (a.z + a.w);
}

// Diamond (L1 radius 3) conv producing a 3x3 output tile. Phase 1 loads the
// entire 48-cell halo into registers as one batch of independent ds_reads
// (single waitcnt, one LDS latency exposure); phase 2 is pure FMA. The 9
// center values arrive in registers (c[]).
// SEL=0: weights (exp(-5d) - eps)      [K local part]
// SEL=1: weights d*(exp(-5d) - eps)    [K*cost local part; d=0 tap is zero]
template <int SEL>
__device__ __forceinline__ void conv_tile(const float* __restrict__ pad, int ip,
                                          const float* __restrict__ c,
                                          float* __restrict__ out) {
  float h[NHALO];
#pragma unroll
  for (int rho = -3; rho <= 5; ++rho) {
    const int w = halo_w(rho);
    const float* rp = pad + ip + rho * PW;
#pragma unroll
    for (int m = -w; m <= 2 + w; ++m) {
      if (rho >= 0 && rho <= 2 && m >= 0 && m <= 2) continue;
      h[h_index(rho, m)] = rp[m];
    }
  }
  __builtin_amdgcn_sched_barrier(0);  // keep the load batch ahead of the math

  float acc[9];
#pragma unroll
  for (int i = 0; i < 9; ++i) acc[i] = 0.f;
#pragma unroll
  for (int r = 0; r < 3; ++r) {
#pragma unroll
    for (int rho = r - 3; rho <= r + 3; ++rho) {
      const int d = (rho - r) < 0 ? r - rho : rho - r;
#pragma unroll
      for (int k = 0; k < 3; ++k) {
#pragma unroll
        for (int m = -3; m <= 3; ++m) {
          if (m < -(3 - d) || m > (3 - d)) continue;
          const int dist = d + (m < 0 ? -m : m);
          float wgt;
          if (SEL == 0) {
            wgt = (dist == 0) ? 1.0f            // 1 - 1e-8 rounds to 1.0f
                : (dist == 1) ? 6.7379370e-3f   // exp(-5)  - 1e-8
                : (dist == 2) ? 4.5389930e-5f   // exp(-10) - 1e-8
                              : 2.9590232e-7f;  // exp(-15) - 1e-8
          } else {
            if (dist == 0) continue;
            wgt = (dist == 1) ? 6.7379370e-3f
                : (dist == 2) ? 9.0779860e-5f   // 2*(exp(-10) - 1e-8)
                              : 8.8770696e-7f;  // 3*(exp(-15) - 1e-8)
          }
          const int cm = k + m;  // column relative to tile
          const float val = (rho >= 0 && rho <= 2 && cm >= 0 && cm <= 2)
                                ? c[rho * 3 + cm]
                                : h[h_index(rho, cm)];
          acc[r * 3 + k] += wgt * val;
        }
      }
    }
  }
#pragma unroll
  for (int i = 0; i < 9; ++i) out[i] = acc[i];
}

__global__ __launch_bounds__(NT, 1) void sinkhorn48(const float* __restrict__ x,
                                                    const float* __restrict__ y,
                                                    float* __restrict__ out) {
  __shared__ float upad[PH * PW];
  __shared__ float vpad[PH * PW];
  __shared__ alignas(16) float rA[4];  // Su partials / x-sum / dist partials
  __shared__ alignas(16) float rB[4];  // Sv partials / y-sum
  __shared__ alignas(16) float rC[4];  // diff^2 partials
  __shared__ float vr[WIDTH];
  __shared__ float vc[WIDTH];

  const int tid = threadIdx.x;
  const int b = blockIdx.x;
  const int r0 = (tid >> 4) * 3;      // 16 row-groups of 3 rows
  const int c0 = (tid & 15) * 3;      // 16 col-groups of 3 cols
  const int ip = (r0 + 3) * PW + (c0 + 3);
  const int wid = tid >> 6;
  const int lane = tid & 63;

  // Zero halos (and interiors) of the padded grids.
  for (int i = tid; i < PH * PW; i += NT) { upad[i] = 0.f; vpad[i] = 0.f; }

  // Load this thread's 3x3 pixels of both images into registers.
  const float* xb = x + b * N;
  const float* yb = y + b * N;
  float xr[9], yr[9];
#pragma unroll
  for (int r = 0; r < 3; ++r)
#pragma unroll
    for (int k = 0; k < 3; ++k) {
      xr[r * 3 + k] = xb[(r0 + r) * WIDTH + c0 + k];
      yr[r * 3 + k] = yb[(r0 + r) * WIDTH + c0 + k];
    }
  {
    float sx = 0.f, sy = 0.f;
#pragma unroll
    for (int i = 0; i < 9; ++i) { sx += xr[i]; sy += yr[i]; }
    sx = wave_sum(sx); sy = wave_sum(sy);
    if (lane == 0) { rA[wid] = sx; rB[wid] = sy; }
  }
  __syncthreads();  // B0: publishes rA/rB partials + zeroed pads
  const float irx = __builtin_amdgcn_rcpf(sum4(rA));
  const float iry = __builtin_amdgcn_rcpf(sum4(rB));
#pragma unroll
  for (int i = 0; i < 9; ++i) { xr[i] *= irx; yr[i] *= iry; }

  float ur[9];
#pragma unroll
  for (int i = 0; i < 9; ++i) ur[i] = 1.0f / (float)N;
#pragma unroll
  for (int r = 0; r < 3; ++r)
#pragma unroll
    for (int k = 0; k < 3; ++k) upad[ip + r * PW + k] = ur[r * 3 + k];
  __syncthreads();  // B1: separates rA/rB reads above from rewrite below
  if (tid < NWAVE) { rA[tid] = 1.0f / (float)NWAVE; rC[tid] = 1.0f; }
  __syncthreads();  // B2: publishes rA (Su(u0)=1), rC dummy, upad interior

  float cc[9], vv[9];
  for (int iter = 0; iter < MAX_ITERS; ++iter) {
    // Partial sums published at the last barrier; independent of the conv, so
    // their read latency hides behind it.
    const float Su = sum4(rA);
    const float dsq = sum4(rC);
    conv_tile<0>(upad, ip, ur, cc);
    // Reference freezes u at the first iter (i>0) with diff<TOL; dsq here is
    // from iteration (iter-1). Break before any state write -> exact match.
    if (iter >= 2 && dsq < TOLSQ) break;
    const float base = EPS * Su;
    float pv = 0.f;
#pragma unroll
    for (int i = 0; i < 9; ++i) {
      vv[i] = yr[i] * __builtin_amdgcn_rcpf(base + cc[i]);
      pv += vv[i];
    }
#pragma unroll
    for (int r = 0; r < 3; ++r)
#pragma unroll
      for (int k = 0; k < 3; ++k) vpad[ip + r * PW + k] = vv[r * 3 + k];
    pv = wave_sum(pv);
    if (lane == 0) rB[wid] = pv;
    __syncthreads();  // A: publishes vpad + Sv partials

    const float Sv = sum4(rB);  // hides behind conv(vpad)
    conv_tile<0>(vpad, ip, vv, cc);
    const float base2 = EPS * Sv;
    float psu = 0.f, pd = 0.f;
#pragma unroll
    for (int i = 0; i < 9; ++i) {
      const float un = xr[i] * __builtin_amdgcn_rcpf(base2 + cc[i]);
      const float d = ur[i] - un;
      ur[i] = un;
      psu += un;
      pd += d * d;
    }
#pragma unroll
    for (int r = 0; r < 3; ++r)
#pragma unroll
      for (int k = 0; k < 3; ++k) upad[ip + r * PW + k] = ur[r * 3 + k];
    psu = wave_sum(psu);
    pd = wave_sum(pd);
    if (lane == 0) { rA[wid] = psu; rC[wid] = pd; }
    __syncthreads();  // B: publishes upad + Su/diff partials
  }

  // Final v from converged u. rA partials match current upad on both exit paths.
  const float SuF = sum4(rA);
  conv_tile<0>(upad, ip, ur, cc);
  const float base = EPS * SuF;
#pragma unroll
  for (int i = 0; i < 9; ++i) vv[i] = yr[i] * __builtin_amdgcn_rcpf(base + cc[i]);
#pragma unroll
  for (int r = 0; r < 3; ++r)
#pragma unroll
    for (int k = 0; k < 3; ++k) vpad[ip + r * PW + k] = vv[r * 3 + k];
  __syncthreads();

  // Row/col marginals of v for the separable eps*(C @ v) term (one-time).
  if (tid < WIDTH) {
    float s = 0.f;
    const float* rp = vpad + (tid + 3) * PW + 3;
    for (int c = 0; c < WIDTH; ++c) s += rp[c];
    vr[tid] = s;
  } else if (tid >= 64 && tid < 64 + WIDTH) {
    const int c = tid - 64;
    float s = 0.f;
    const float* cp = vpad + 3 * PW + 3 + c;
    for (int r = 0; r < WIDTH; ++r) s += cp[r * PW];
    vc[c] = s;
  }
  __syncthreads();

  // dist_b = sum_j u_j * ( eps*(Cv)_j + distance-weighted local conv )
  float aD[9];
  conv_tile<1>(vpad, ip, vv, aD);
  float part = 0.f;
#pragma unroll
  for (int r = 0; r < 3; ++r) {
    const int rr = r0 + r;
    float cvr = 0.f;
    for (int q = 0; q < WIDTH; ++q) cvr += vr[q] * fabsf((float)(q - rr));
#pragma unroll
    for (int k = 0; k < 3; ++k) {
      const int ccol = c0 + k;
      float cvc = 0.f;
      for (int q = 0; q < WIDTH; ++q) cvc += vc[q] * fabsf((float)(q - ccol));
      part += ur[r * 3 + k] * (EPS * (cvr + cvc) + aD[r * 3 + k]);
    }
  }
  {
    const float p = wave_sum(part);
    if (lane == 0) rA[wid] = p;  // WAR on rA separated by the two barriers above
  }
  __syncthreads();
  if (tid == 0) out[b] = sum4(rA);
}

extern "C" void kernel_launch(void* const* d_in, const int* in_sizes, int n_in,
                              void* d_out, int out_size, void* d_ws, size_t ws_size,
                              hipStream_t stream) {
  const float* x = (const float*)d_in[0];
  const float* y = (const float*)d_in[1];
  float* out = (float*)d_out;
  sinkhorn48<<<BATCH, NT, 0, stream>>>(x, y, out);
}